// Round 30
// baseline (115.605 us; speedup 1.0000x reference)
//
#include <hip/hip_runtime.h>
#include <math.h>

#define EMBED 1024
#define NH    16
#define DH    64
#define BATCH 2
#define SEQ   2048
#define MTOT  4096
#define BHTOT 32

typedef float f32x4  __attribute__((ext_vector_type(4)));
typedef float f32x16 __attribute__((ext_vector_type(16)));
typedef short s16x8  __attribute__((ext_vector_type(8)));
typedef short s16x4  __attribute__((ext_vector_type(4)));
typedef unsigned u32x2 __attribute__((ext_vector_type(2)));
typedef unsigned u32x4 __attribute__((ext_vector_type(4)));

#define AS1 __attribute__((address_space(1)))
#define AS3 __attribute__((address_space(3)))

__device__ __forceinline__ unsigned short bf16_rne(float f) {
    unsigned u = __builtin_bit_cast(unsigned, f);
    return (unsigned short)((u + 0x7FFFu + ((u >> 16) & 1u)) >> 16);
}
__device__ __forceinline__ void gload16(const void* g, void* l) {
    __builtin_amdgcn_global_load_lds((const AS1 void*)g, (AS3 void*)l, 16, 0, 0);
}
__device__ __forceinline__ unsigned cvt_pk_bf16(float lo, float hi) {
    unsigned r;
    asm volatile("v_cvt_pk_bf16_f32 %0, %1, %2" : "=v"(r) : "v"(lo), "v"(hi));
    return r;
}
// raw v_exp_f32: computes 2^x in one VALU op; x=-inf -> 0
#define EXP2(x) __builtin_amdgcn_exp2f(x)
#define MFMA16(a, b, c) __builtin_amdgcn_mfma_f32_16x16x32_bf16((a), (b), (c), 0, 0, 0)
#define MFMA32(a, b, c) __builtin_amdgcn_mfma_f32_32x32x16_bf16((a), (b), (c), 0, 0, 0)

// ---------------------------------------------------------------------------
// prep: splitX (blocks [0,2048)), Wkqv^T hi-only ([2048,5120)),
// Wout^T hi-only ([5120,6144)). WoT lives in a permanently-free ws hole.
// ---------------------------------------------------------------------------
__global__ __launch_bounds__(256)
void prep_kernel(const float* __restrict__ X, const float* __restrict__ Wkqv,
                 const float* __restrict__ Wout,
                 unsigned short* __restrict__ Xh,
                 unsigned short* __restrict__ WhT,
                 unsigned short* __restrict__ WoTh)
{
    __shared__ float T[32][33];
    const int bid = blockIdx.x, tid = threadIdx.x;

    if (bid < 2048) {   // ---- splitX: X fp32 -> Xh bf16
        const size_t i = ((size_t)bid * 256 + tid) * 8;
        float4 a = *(const float4*)&X[i];
        float4 b = *(const float4*)&X[i + 4];
        float v[8] = {a.x, a.y, a.z, a.w, b.x, b.y, b.z, b.w};
        s16x8 h8;
#pragma unroll
        for (int e = 0; e < 8; ++e) h8[e] = (short)bf16_rne(v[e]);
        *(s16x8*)&Xh[i] = h8;
        return;
    }

    const float* W;
    unsigned short* Hi;
    int Nd, n0, k0;
    if (bid < 5120) {
        const int u = bid - 2048;
        W = Wkqv; Hi = WhT; Nd = 3072;
        n0 = (u % 96) * 32; k0 = (u / 96) * 32;
    } else {
        const int u = bid - 5120;
        W = Wout; Hi = WoTh; Nd = 1024;
        n0 = (u & 31) * 32; k0 = (u >> 5) * 32;
    }
    constexpr int Kd = 1024;
    {
        const int row = tid >> 3, c4 = (tid & 7) * 4;
        float4 v = *(const float4*)&W[(size_t)(k0 + row) * Nd + n0 + c4];
        T[row][c4] = v.x; T[row][c4 + 1] = v.y; T[row][c4 + 2] = v.z; T[row][c4 + 3] = v.w;
    }
    __syncthreads();
    {
        const int nr = tid >> 3, c4 = (tid & 7) * 4;
        s16x4 h4;
#pragma unroll
        for (int e = 0; e < 4; ++e) h4[e] = (short)bf16_rne(T[c4 + e][nr]);
        *(s16x4*)&Hi[(size_t)(n0 + nr) * Kd + k0 + c4] = h4;
    }
}

// ---------------------------------------------------------------------------
// QKV GEMM: pure bf16 (1-combo), mfma_32x32x16, 128x128 tile, BK=32,
// TRIPLE-buffered 48 KB LDS with counted-vmcnt pipeline: stage(it+2) ->
// vmcnt(8) (tiles it+1/it+2 stay in flight across the barrier) -> raw
// s_barrier -> compute buf[it%3] -> raw s_barrier. Loads get 2 compute
// phases of latency cover. XCD swizzle, hi-only outputs, Q pre-scaled by
// 0.125*log2e.
// ---------------------------------------------------------------------------
__global__ __launch_bounds__(256)
void qkv_gemm_kernel(const unsigned short* __restrict__ Xh_g,
                     const unsigned short* __restrict__ BhT,
                     const float* __restrict__ bias,
                     unsigned short* __restrict__ Qh,
                     unsigned short* __restrict__ Kh,
                     unsigned short* __restrict__ Vh)
{
    constexpr int KD = 1024;
    __shared__ __align__(16) short SB[3][8192];   // 48 KB: 3 bufs x {A,B}

    const int tid = threadIdx.x, lane = tid & 63, wid = tid >> 6;
    const int l31 = lane & 31, l5 = lane >> 5;
    const int wm = wid >> 1, wn = wid & 1;

    const int bid = blockIdx.x;
    const int u = bid >> 3, xcd = bid & 7;
    const int by = xcd * 4 + (u & 3);   // m-tile 0..31
    const int bx = u >> 2;              // n-tile 0..23
    const int m0 = by * 128, n0 = bx * 128;

    f32x16 acc[2][2];
#pragma unroll
    for (int i = 0; i < 2; ++i)
#pragma unroll
        for (int j = 0; j < 2; ++j)
#pragma unroll
            for (int e = 0; e < 16; ++e) acc[i][j][e] = 0.f;

    const int srow = lane >> 2, ss = lane & 3;

    // 4 staging loads per wave per tile (A x 8 segs + B x 8 segs over 4 waves)
#define QK_STAGE(buf, k0_)                                                     \
    {                                                                          \
        _Pragma("unroll")                                                      \
        for (int i = 0; i < 4; ++i) {                                          \
            const int s = wid * 4 + i;                                         \
            const int t = s >> 3, j = s & 7;                                   \
            const unsigned short* gsrc = (t == 0) ? Xh_g : BhT;                \
            const int roff = (t == 0) ? m0 : n0;                               \
            const int row_loc = j * 16 + srow;                                 \
            const int kc = ss ^ ((row_loc >> 1) & 3);                          \
            gload16(gsrc + (size_t)(roff + row_loc) * KD + (k0_) + kc * 8,     \
                    &SB[buf][t * 4096 + j * 512]);                             \
        }                                                                      \
    }

    // prologue: stage tiles 0 and 1 (8 loads in flight per wave)
    QK_STAGE(0, 0)
    QK_STAGE(1, 32)

    for (int it = 0; it < 32; ++it) {
        const int cur = it % 3;
        if (it + 2 < 32) {
            QK_STAGE((it + 2) % 3, (it + 2) * 32)
            // 12 outstanding; wait tile it's 4, leave 8 (tiles it+1, it+2)
            asm volatile("s_waitcnt vmcnt(8)" ::: "memory");
        } else if (it + 1 < 32) {
            // 8 outstanding (tiles it, it+1); wait tile it's 4
            asm volatile("s_waitcnt vmcnt(4)" ::: "memory");
        } else {
            asm volatile("s_waitcnt vmcnt(0)" ::: "memory");
        }
        __builtin_amdgcn_s_barrier();        // all waves: buf[cur] fully landed
        __builtin_amdgcn_sched_barrier(0);   // rule 18: no hoisting past wait

        const short* Ahp = &SB[cur][0];
        const short* Bhp = &SB[cur][4096];

        s16x8 fa[2][2], fbh[2][2];
#pragma unroll
        for (int am = 0; am < 2; ++am) {
            const int row = wm * 64 + am * 32 + l31;
            const int sw = (row >> 1) & 3;
#pragma unroll
            for (int kh2 = 0; kh2 < 2; ++kh2) {
                const int sl = ((kh2 * 2 + l5) ^ sw) * 8;
                fa[am][kh2] = *(const s16x8*)&Ahp[row * 32 + sl];
            }
        }
#pragma unroll
        for (int bn = 0; bn < 2; ++bn) {
            const int row = wn * 64 + bn * 32 + l31;
            const int sw = (row >> 1) & 3;
#pragma unroll
            for (int kh2 = 0; kh2 < 2; ++kh2) {
                const int sl = ((kh2 * 2 + l5) ^ sw) * 8;
                fbh[bn][kh2] = *(const s16x8*)&Bhp[row * 32 + sl];
            }
        }
#pragma unroll
        for (int kh2 = 0; kh2 < 2; ++kh2)
#pragma unroll
            for (int am = 0; am < 2; ++am)
#pragma unroll
                for (int bn = 0; bn < 2; ++bn)
                    acc[am][bn] = MFMA32(fa[am][kh2], fbh[bn][kh2], acc[am][bn]);

        // readers of buf[cur] done; safe for re-stage at iter it+1
        __builtin_amdgcn_s_barrier();
    }
#undef QK_STAGE

    // epilogue (D: col=l31, row=(r&3)+8*(r>>2)+4*l5); hi-only outputs
    const float QSCALE = 0.125f * 1.44269504f;   // fold log2e -> exp2 softmax
#pragma unroll
    for (int am = 0; am < 2; ++am)
#pragma unroll
        for (int bn = 0; bn < 2; ++bn) {
            const int n = n0 + wn * 64 + bn * 32 + l31;
            const float bv = bias[n];
            const int sec = n >> 10, cc = n & 1023, h = cc >> 6, d = cc & 63;
#pragma unroll
            for (int r = 0; r < 16; ++r) {
                const int mrow = (r & 3) + 8 * (r >> 2) + 4 * l5;
                const int m = m0 + wm * 64 + am * 32 + mrow;
                const int bb = m >> 11, t = m & 2047;
                const int bh_i = bb * NH + h;
                float val = acc[am][bn][r] + bv;
                if (sec == 0) {
                    size_t idx = ((size_t)bh_i * SEQ + t) * DH + d;
                    Qh[idx] = bf16_rne(val * QSCALE);
                } else if (sec == 1) {
                    size_t idx = ((size_t)bh_i * SEQ + t) * DH + d;
                    Kh[idx] = bf16_rne(val);
                } else {
                    size_t idx = ((size_t)bh_i * DH + d) * SEQ + t;   // V transposed
                    Vh[idx] = bf16_rne(val);
                }
            }
        }
}

// ---------------------------------------------------------------------------
// Attention: all-bf16, KVBLK=64. QK^T 1-combo; PV 1-combo. Softmax in
// exp2 units via raw v_exp_f32 (serial-chain form). {Kh,Vh} dbuf 32 KB LDS,
// 16-segment staging (4/wave). Defer-max THR=8. Y hi-only out. (r27 exact)
// ---------------------------------------------------------------------------
__global__ __launch_bounds__(256)
void attn_kernel(const unsigned short* __restrict__ Qh_g,
                 const unsigned short* __restrict__ Kh_g,
                 const unsigned short* __restrict__ Vh_g,
                 unsigned short* __restrict__ Yh)
{
    __shared__ __align__(16) short SM[2][8192];   // 32 KB: 2 bufs x {Kh,Vh}

    const int tid = threadIdx.x, lane = tid & 63, wid = tid >> 6;
    const int l31 = lane & 31, l5 = lane >> 5;
    const int bid = blockIdx.x;
    const int qb = 15 - (bid >> 5), bh = bid & 31;   // heavy q-tiles first
    const int Q0 = qb * 128;
    const int qg = Q0 + wid * 32 + l31;              // this lane's q row

    // Q fragments from global (once per block)
    s16x8 qfh[4];
    {
        const size_t qo = ((size_t)bh * SEQ + qg) * DH;
#pragma unroll
        for (int t = 0; t < 4; ++t) {
            const int ch = t * 2 + l5;
            qfh[t] = *(const s16x8*)&Qh_g[qo + ch * 8];
        }
    }

    float m_i = -INFINITY, l_i = 0.f;
    f32x16 yacc[2];
#pragma unroll
    for (int e = 0; e < 16; ++e) { yacc[0][e] = 0.f; yacc[1][e] = 0.f; }

    const int srow = lane >> 3, ss = lane & 7;
    const int KT = 2 * qb + 2;

    {
#pragma unroll
        for (int i = 0; i < 4; ++i) {
            const int s = wid * 4 + i;
            const int t = s >> 3, j = s & 7;
            const int row = j * 8 + srow;
            const int kc = ss ^ (row & 7);
            const unsigned short* src = (t == 0)
                ? Kh_g + ((size_t)bh * SEQ + row) * DH + kc * 8
                : Vh_g + ((size_t)bh * DH + row) * SEQ + kc * 8;
            gload16(src, &SM[0][t * 4096 + j * 512]);
        }
    }

    for (int kt = 0; kt < KT; ++kt) {
        const int cur = kt & 1;
        __syncthreads();   // stage(kt) landed; reads of buf[cur] (kt-2) done
        if (kt + 1 < KT) {
            const int kn = (kt + 1) * 64;
#pragma unroll
            for (int i = 0; i < 4; ++i) {
                const int s = wid * 4 + i;
                const int t = s >> 3, j = s & 7;
                const int row = j * 8 + srow;
                const int kc = ss ^ (row & 7);
                const unsigned short* src = (t == 0)
                    ? Kh_g + ((size_t)bh * SEQ + kn + row) * DH + kc * 8
                    : Vh_g + ((size_t)bh * DH + row) * SEQ + kn + kc * 8;
                gload16(src, &SM[cur ^ 1][t * 4096 + j * 512]);
            }
        }

        if (kt * 64 > Q0 + wid * 32 + 31) continue;   // fully masked for this wave

        const short* Ksh = &SM[cur][0];
        const short* Vsh = &SM[cur][4096];

        // ---- S^T = K . Q  (1-combo; interleaved kb -> distance-2 chains)
        f32x16 s[2];
#pragma unroll
        for (int e = 0; e < 16; ++e) { s[0][e] = 0.f; s[1][e] = 0.f; }
#pragma unroll
        for (int t = 0; t < 4; ++t) {
            s16x8 kh[2];
#pragma unroll
            for (int kb = 0; kb < 2; ++kb) {
                const int row = kb * 32 + l31;
                const int sl = ((t * 2 + l5) ^ (row & 7)) * 8;
                kh[kb] = *(const s16x8*)&Ksh[row * 64 + sl];
            }
#pragma unroll
            for (int kb = 0; kb < 2; ++kb) s[kb] = MFMA32(kh[kb], qfh[t], s[kb]);
        }

        // ---- causal mask (only near the diagonal)
        if (kt * 64 + 63 > Q0 + wid * 32) {
#pragma unroll
            for (int kb = 0; kb < 2; ++kb)
#pragma unroll
                for (int r = 0; r < 16; ++r) {
                    const int key = kt * 64 + kb * 32 + (r & 3) + 8 * (r >> 2) + 4 * l5;
                    if (key > qg) s[kb][r] = -INFINITY;
                }
        }

        // ---- online softmax in exp2 units, defer-max THR=8 (P <= 2^8)
        float mx = s[0][0];
#pragma unroll
        for (int r = 1; r < 16; ++r) mx = fmaxf(mx, s[0][r]);
#pragma unroll
        for (int r = 0; r < 16; ++r) mx = fmaxf(mx, s[1][r]);
        mx = fmaxf(mx, __shfl_xor(mx, 32));
        const bool defer = (__all(mx - m_i <= 8.f) != 0);
        float mref;
        if (defer) {
            mref = m_i;
        } else {
            mref = fmaxf(m_i, mx);
            const float al = EXP2(m_i - mref);
            m_i = mref;
            l_i *= al;
#pragma unroll
            for (int e = 0; e < 16; ++e) { yacc[0][e] *= al; yacc[1][e] *= al; }
        }
        float ls = 0.f;
#pragma unroll
        for (int kb = 0; kb < 2; ++kb)
#pragma unroll
            for (int r = 0; r < 16; ++r) {
                s[kb][r] = EXP2(s[kb][r] - mref);
                ls += s[kb][r];
            }
        ls += __shfl_xor(ls, 32);
        l_i += ls;

        // ---- P (bf16) fragments in-register: cvt_pk + permlane32_swap
        unsigned pk[2][8];
#pragma unroll
        for (int kb = 0; kb < 2; ++kb)
#pragma unroll
            for (int j = 0; j < 8; ++j)
                pk[kb][j] = cvt_pk_bf16(s[kb][2 * j], s[kb][2 * j + 1]);
        s16x8 pf[2][2];
#pragma unroll
        for (int kb = 0; kb < 2; ++kb) {
            u32x2 sA = __builtin_amdgcn_permlane32_swap(pk[kb][0], pk[kb][2], false, false);
            u32x2 sB = __builtin_amdgcn_permlane32_swap(pk[kb][1], pk[kb][3], false, false);
            u32x4 w0 = {sA[0], sB[0], sA[1], sB[1]};
            pf[kb][0] = __builtin_bit_cast(s16x8, w0);
            u32x2 sC = __builtin_amdgcn_permlane32_swap(pk[kb][4], pk[kb][6], false, false);
            u32x2 sD = __builtin_amdgcn_permlane32_swap(pk[kb][5], pk[kb][7], false, false);
            u32x4 w1 = {sC[0], sD[0], sC[1], sD[1]};
            pf[kb][1] = __builtin_bit_cast(s16x8, w1);
        }

        // ---- Y^T += V^T . P  (1-combo; interleaved dt -> distance-2 chains)
#pragma unroll
        for (int t = 0; t < 4; ++t) {
            s16x8 vh[2];
#pragma unroll
            for (int dt = 0; dt < 2; ++dt) {
                const int row = dt * 32 + l31;
                const int sl = ((t * 2 + l5) ^ (row & 7)) * 8;
                vh[dt] = *(const s16x8*)&Vsh[row * 64 + sl];
            }
            const s16x8 pfr = pf[t >> 1][t & 1];
#pragma unroll
            for (int dt = 0; dt < 2; ++dt) yacc[dt] = MFMA32(vh[dt], pfr, yacc[dt]);
        }
    }

    // ---- epilogue: normalize, hi-only bf16, LDS transpose bounce, write Yh
    __syncthreads();   // everyone done with K/V LDS
    short* SMf = &SM[0][0];
    const float inv = 1.f / l_i;
    const int qlcl = wid * 32 + l31;
#pragma unroll
    for (int dt = 0; dt < 2; ++dt)
#pragma unroll
        for (int rq = 0; rq < 4; ++rq) {
            const int d0 = dt * 32 + rq * 8 + 4 * l5;
            s16x4 h4;
#pragma unroll
            for (int c = 0; c < 4; ++c)
                h4[c] = (short)bf16_rne(yacc[dt][rq * 4 + c] * inv);
            const int base = qlcl * 64 + (((d0 >> 3) ^ (qlcl & 7)) * 8) + (d0 & 7);
            *(s16x4*)&SMf[base] = h4;
        }
    __syncthreads();
    const int b = bh >> 4, h = bh & 15;
#pragma unroll
    for (int i = 0; i < 4; ++i) {
        const int idx = tid + i * 256;
        const int row = idx >> 3, ch = idx & 7;
        const int sl = (ch ^ (row & 7)) * 8;
        s16x8 vh8 = *(const s16x8*)&SMf[row * 64 + sl];
        const size_t o = ((size_t)(b * SEQ + Q0 + row)) * EMBED + h * DH + ch * 8;
        *(s16x8*)&Yh[o] = vh8;
    }
}

// ---------------------------------------------------------------------------
// Out GEMM: pure bf16, 128x64 tile (grid 512 = 2 blocks/CU), dbuf 24 KB,
// 12-segment issue-early staging (3/wave), XCD swizzle (4m x 16n per XCD).
// (r27 exact)
// ---------------------------------------------------------------------------
__global__ __launch_bounds__(256)
void out_gemm_kernel(const unsigned short* __restrict__ Yh_g,
                     const unsigned short* __restrict__ WhT,
                     const float* __restrict__ bias, float* __restrict__ out)
{
    constexpr int KD = 1024, ND = 1024;
    // per buf (shorts): A [0,4096) = [128][32], B [4096,6144) = [64][32]
    __shared__ __align__(16) short SB[2][6144];   // 24 KB

    const int tid = threadIdx.x, lane = tid & 63, wid = tid >> 6;
    const int g = lane >> 4, ln = lane & 15;
    const int wm = wid >> 1, wn = wid & 1;

    const int bid = blockIdx.x;
    const int u = bid >> 3, xcd = bid & 7;
    const int by = xcd * 4 + (u & 3);   // m-tile 0..31
    const int bx = u >> 2;              // n-tile 0..15
    const int m0 = by * 128, n0 = bx * 64;

    f32x4 acc[4][2];
#pragma unroll
    for (int i = 0; i < 4; ++i)
#pragma unroll
        for (int j = 0; j < 2; ++j) acc[i][j] = (f32x4){0.f, 0.f, 0.f, 0.f};

    const int srow = lane >> 2, ss = lane & 3;

    // staging: 12 segments (A x 8, B x 4); 3 per wave
#define OG_STAGE(buf, k0_)                                                     \
    {                                                                          \
        _Pragma("unroll")                                                      \
        for (int i = 0; i < 3; ++i) {                                          \
            const int s = wid * 3 + i;                                         \
            const bool isA = (s < 8);                                          \
            const int j = isA ? s : (s - 8);                                   \
            const int row_loc = j * 16 + srow;                                 \
            const int kc = ss ^ ((row_loc >> 1) & 3);                          \
            const unsigned short* src = isA                                    \
                ? Yh_g + (size_t)(m0 + row_loc) * KD + (k0_) + kc * 8          \
                : WhT + (size_t)(n0 + row_loc) * KD + (k0_) + kc * 8;          \
            gload16(src, &SB[buf][(isA ? 0 : 4096) + j * 512]);                \
        }                                                                      \
    }

    OG_STAGE(0, 0)

    for (int it = 0; it < 32; ++it) {
        const int cur = it & 1;
        __syncthreads();
        if (it + 1 < 32) OG_STAGE(cur ^ 1, (it + 1) * 32)

        const short* Ah = &SB[cur][0];
        const short* Bh = &SB[cur][4096];

        s16x8 fah[4], fbh[2];
#pragma unroll
        for (int am = 0; am < 4; ++am) {
            int m_loc = wm * 64 + am * 16 + ln;
            int sl = (g ^ ((m_loc >> 1) & 3)) * 8;
            fah[am] = *(const s16x8*)&Ah[m_loc * 32 + sl];
        }
#pragma unroll
        for (int bn = 0; bn < 2; ++bn) {
            int n_loc = wn * 32 + bn * 16 + ln;
            int sl = (g ^ ((n_loc >> 1) & 3)) * 8;
            fbh[bn] = *(const s16x8*)&Bh[n_loc * 32 + sl];
        }
#pragma unroll
        for (int am = 0; am < 4; ++am)
#pragma unroll
            for (int bn = 0; bn < 2; ++bn)
                acc[am][bn] = MFMA16(fah[am], fbh[bn], acc[am][bn]);
    }
#undef OG_STAGE

#pragma unroll
    for (int am = 0; am < 4; ++am)
#pragma unroll
        for (int bn = 0; bn < 2; ++bn) {
            int n = n0 + wn * 32 + bn * 16 + ln;
            float bv = bias[n];
#pragma unroll
            for (int r = 0; r < 4; ++r) {
                int m = m0 + wm * 64 + am * 16 + g * 4 + r;
                out[(size_t)m * ND + n] = acc[am][bn][r] + bv;
            }
        }
}

// ---------------------------------------------------------------------------
extern "C" void kernel_launch(void* const* d_in, const int* in_sizes, int n_in,
                              void* d_out, int out_size, void* d_ws, size_t ws_size,
                              hipStream_t stream)
{
    const float* x     = (const float*)d_in[0];
    const float* W_kqv = (const float*)d_in[1];
    const float* b_kqv = (const float*)d_in[2];
    const float* W_out = (const float*)d_in[3];
    const float* b_out = (const float*)d_in[4];
    float* out = (float*)d_out;

    char* ws = (char*)d_ws;
    const size_t MB = 1024 * 1024;
    // ws map (64 MB): Qh [0,8) | WoTh [8,10) | Kh [16,24) | Vh [32,40)
    //                 WhT [48,54) then Yh [48,56) after qkv
    unsigned short* Qh   = (unsigned short*)(ws);
    unsigned short* WoTh = (unsigned short*)(ws + 8 * MB);   // permanently free hole
    unsigned short* Kh   = Qh + 8388608;    // ws+16MB
    unsigned short* Vh   = Kh + 8388608;    // ws+32MB
    unsigned short* WhT  = (unsigned short*)(ws + 48 * MB);
    unsigned short* Yh   = (unsigned short*)(ws + 48 * MB);  // overwrites WhT post-qkv
    // Xh lives in d_out (8 MB of 16): dead until out_gemm rewrites all of it.
    unsigned short* Xh = (unsigned short*)d_out;

    prep_kernel<<<dim3(6144), 256, 0, stream>>>(
        x, W_kqv, W_out, Xh, WhT, WoTh);
    qkv_gemm_kernel<<<dim3(768), 256, 0, stream>>>(
        Xh, WhT, b_kqv, Qh, Kh, Vh);
    attn_kernel<<<dim3(BHTOT * (SEQ / 128)), 256, 0, stream>>>(
        Qh, Kh, Vh, Yh);
    out_gemm_kernel<<<dim3(512), 256, 0, stream>>>(
        Yh, WoTh, b_out, out);
}

// Round 31
// 114.413 us; speedup vs baseline: 1.0104x; 1.0104x over previous
//
#include <hip/hip_runtime.h>
#include <math.h>

#define EMBED 1024
#define NH    16
#define DH    64
#define BATCH 2
#define SEQ   2048
#define MTOT  4096
#define BHTOT 32

typedef float f32x4  __attribute__((ext_vector_type(4)));
typedef float f32x16 __attribute__((ext_vector_type(16)));
typedef short s16x8  __attribute__((ext_vector_type(8)));
typedef short s16x4  __attribute__((ext_vector_type(4)));
typedef unsigned u32x2 __attribute__((ext_vector_type(2)));
typedef unsigned u32x4 __attribute__((ext_vector_type(4)));

#define AS1 __attribute__((address_space(1)))
#define AS3 __attribute__((address_space(3)))

__device__ __forceinline__ unsigned short bf16_rne(float f) {
    unsigned u = __builtin_bit_cast(unsigned, f);
    return (unsigned short)((u + 0x7FFFu + ((u >> 16) & 1u)) >> 16);
}
__device__ __forceinline__ void gload16(const void* g, void* l) {
    __builtin_amdgcn_global_load_lds((const AS1 void*)g, (AS3 void*)l, 16, 0, 0);
}
__device__ __forceinline__ unsigned cvt_pk_bf16(float lo, float hi) {
    unsigned r;
    asm volatile("v_cvt_pk_bf16_f32 %0, %1, %2" : "=v"(r) : "v"(lo), "v"(hi));
    return r;
}
// raw v_exp_f32: computes 2^x in one VALU op; x=-inf -> 0
#define EXP2(x) __builtin_amdgcn_exp2f(x)
#define MFMA16(a, b, c) __builtin_amdgcn_mfma_f32_16x16x32_bf16((a), (b), (c), 0, 0, 0)
#define MFMA32(a, b, c) __builtin_amdgcn_mfma_f32_32x32x16_bf16((a), (b), (c), 0, 0, 0)

// ---------------------------------------------------------------------------
// prep: splitX (blocks [0,2048)), Wkqv^T hi-only ([2048,5120)),
// Wout^T hi-only ([5120,6144)). WoT lives in a permanently-free ws hole.
// ---------------------------------------------------------------------------
__global__ __launch_bounds__(256)
void prep_kernel(const float* __restrict__ X, const float* __restrict__ Wkqv,
                 const float* __restrict__ Wout,
                 unsigned short* __restrict__ Xh,
                 unsigned short* __restrict__ WhT,
                 unsigned short* __restrict__ WoTh)
{
    __shared__ float T[32][33];
    const int bid = blockIdx.x, tid = threadIdx.x;

    if (bid < 2048) {   // ---- splitX: X fp32 -> Xh bf16
        const size_t i = ((size_t)bid * 256 + tid) * 8;
        float4 a = *(const float4*)&X[i];
        float4 b = *(const float4*)&X[i + 4];
        float v[8] = {a.x, a.y, a.z, a.w, b.x, b.y, b.z, b.w};
        s16x8 h8;
#pragma unroll
        for (int e = 0; e < 8; ++e) h8[e] = (short)bf16_rne(v[e]);
        *(s16x8*)&Xh[i] = h8;
        return;
    }

    const float* W;
    unsigned short* Hi;
    int Nd, n0, k0;
    if (bid < 5120) {
        const int u = bid - 2048;
        W = Wkqv; Hi = WhT; Nd = 3072;
        n0 = (u % 96) * 32; k0 = (u / 96) * 32;
    } else {
        const int u = bid - 5120;
        W = Wout; Hi = WoTh; Nd = 1024;
        n0 = (u & 31) * 32; k0 = (u >> 5) * 32;
    }
    constexpr int Kd = 1024;
    {
        const int row = tid >> 3, c4 = (tid & 7) * 4;
        float4 v = *(const float4*)&W[(size_t)(k0 + row) * Nd + n0 + c4];
        T[row][c4] = v.x; T[row][c4 + 1] = v.y; T[row][c4 + 2] = v.z; T[row][c4 + 3] = v.w;
    }
    __syncthreads();
    {
        const int nr = tid >> 3, c4 = (tid & 7) * 4;
        s16x4 h4;
#pragma unroll
        for (int e = 0; e < 4; ++e) h4[e] = (short)bf16_rne(T[c4 + e][nr]);
        *(s16x4*)&Hi[(size_t)(n0 + nr) * Kd + k0 + c4] = h4;
    }
}

// ---------------------------------------------------------------------------
// QKV GEMM: pure bf16 (1-combo), mfma_32x32x16, 128x128 tile, BK=32,
// dbuf 32 KB LDS, issue-early staging (4/wave), XCD swizzle. Hi-only outs.
// Q pre-scaled by 0.125*log2e (softmax runs in exp2 units).
// ---------------------------------------------------------------------------
__global__ __launch_bounds__(256)
void qkv_gemm_kernel(const unsigned short* __restrict__ Xh_g,
                     const unsigned short* __restrict__ BhT,
                     const float* __restrict__ bias,
                     unsigned short* __restrict__ Qh,
                     unsigned short* __restrict__ Kh,
                     unsigned short* __restrict__ Vh)
{
    constexpr int KD = 1024;
    __shared__ __align__(16) short SB[2][8192];   // 32 KB

    const int tid = threadIdx.x, lane = tid & 63, wid = tid >> 6;
    const int l31 = lane & 31, l5 = lane >> 5;
    const int wm = wid >> 1, wn = wid & 1;

    const int bid = blockIdx.x;
    const int u = bid >> 3, xcd = bid & 7;
    const int by = xcd * 4 + (u & 3);   // m-tile 0..31
    const int bx = u >> 2;              // n-tile 0..23
    const int m0 = by * 128, n0 = bx * 128;

    f32x16 acc[2][2];
#pragma unroll
    for (int i = 0; i < 2; ++i)
#pragma unroll
        for (int j = 0; j < 2; ++j)
#pragma unroll
            for (int e = 0; e < 16; ++e) acc[i][j][e] = 0.f;

    const int srow = lane >> 2, ss = lane & 3;

    {
#pragma unroll
        for (int i = 0; i < 4; ++i) {
            const int s = wid * 4 + i;
            const int t = s >> 3, j = s & 7;
            const unsigned short* gsrc = (t == 0) ? Xh_g : BhT;
            const int roff = (t == 0) ? m0 : n0;
            const int row_loc = j * 16 + srow;
            const int kc = ss ^ ((row_loc >> 1) & 3);
            gload16(gsrc + (size_t)(roff + row_loc) * KD + kc * 8,
                    &SB[0][t * 4096 + j * 512]);
        }
    }

    for (int it = 0; it < 32; ++it) {
        const int cur = it & 1;
        __syncthreads();
        if (it + 1 < 32) {
            const int k0n = (it + 1) * 32;
#pragma unroll
            for (int i = 0; i < 4; ++i) {
                const int s = wid * 4 + i;
                const int t = s >> 3, j = s & 7;
                const unsigned short* gsrc = (t == 0) ? Xh_g : BhT;
                const int roff = (t == 0) ? m0 : n0;
                const int row_loc = j * 16 + srow;
                const int kc = ss ^ ((row_loc >> 1) & 3);
                gload16(gsrc + (size_t)(roff + row_loc) * KD + k0n + kc * 8,
                        &SB[cur ^ 1][t * 4096 + j * 512]);
            }
        }
        const short* Ahp = &SB[cur][0];
        const short* Bhp = &SB[cur][4096];

        s16x8 fa[2][2], fbh[2][2];
#pragma unroll
        for (int am = 0; am < 2; ++am) {
            const int row = wm * 64 + am * 32 + l31;
            const int sw = (row >> 1) & 3;
#pragma unroll
            for (int kh2 = 0; kh2 < 2; ++kh2) {
                const int sl = ((kh2 * 2 + l5) ^ sw) * 8;
                fa[am][kh2] = *(const s16x8*)&Ahp[row * 32 + sl];
            }
        }
#pragma unroll
        for (int bn = 0; bn < 2; ++bn) {
            const int row = wn * 64 + bn * 32 + l31;
            const int sw = (row >> 1) & 3;
#pragma unroll
            for (int kh2 = 0; kh2 < 2; ++kh2) {
                const int sl = ((kh2 * 2 + l5) ^ sw) * 8;
                fbh[bn][kh2] = *(const s16x8*)&Bhp[row * 32 + sl];
            }
        }
#pragma unroll
        for (int kh2 = 0; kh2 < 2; ++kh2)
#pragma unroll
            for (int am = 0; am < 2; ++am)
#pragma unroll
                for (int bn = 0; bn < 2; ++bn)
                    acc[am][bn] = MFMA32(fa[am][kh2], fbh[bn][kh2], acc[am][bn]);
    }

    // epilogue (D: col=l31, row=(r&3)+8*(r>>2)+4*l5); hi-only outputs
    const float QSCALE = 0.125f * 1.44269504f;   // fold log2e -> exp2 softmax
#pragma unroll
    for (int am = 0; am < 2; ++am)
#pragma unroll
        for (int bn = 0; bn < 2; ++bn) {
            const int n = n0 + wn * 64 + bn * 32 + l31;
            const float bv = bias[n];
            const int sec = n >> 10, cc = n & 1023, h = cc >> 6, d = cc & 63;
#pragma unroll
            for (int r = 0; r < 16; ++r) {
                const int mrow = (r & 3) + 8 * (r >> 2) + 4 * l5;
                const int m = m0 + wm * 64 + am * 32 + mrow;
                const int bb = m >> 11, t = m & 2047;
                const int bh_i = bb * NH + h;
                float val = acc[am][bn][r] + bv;
                if (sec == 0) {
                    size_t idx = ((size_t)bh_i * SEQ + t) * DH + d;
                    Qh[idx] = bf16_rne(val * QSCALE);
                } else if (sec == 1) {
                    size_t idx = ((size_t)bh_i * SEQ + t) * DH + d;
                    Kh[idx] = bf16_rne(val);
                } else {
                    size_t idx = ((size_t)bh_i * DH + d) * SEQ + t;   // V transposed
                    Vh[idx] = bf16_rne(val);
                }
            }
        }
}

// ---------------------------------------------------------------------------
// Attention: all-bf16, KVBLK=64. QK^T 1-combo; PV 1-combo. Softmax in
// exp2 units via raw v_exp_f32 (serial-chain form). {Kh,Vh} dbuf 32 KB LDS,
// 16-segment staging (4/wave). Defer-max THR=8. Y hi-only out.
// ---------------------------------------------------------------------------
__global__ __launch_bounds__(256)
void attn_kernel(const unsigned short* __restrict__ Qh_g,
                 const unsigned short* __restrict__ Kh_g,
                 const unsigned short* __restrict__ Vh_g,
                 unsigned short* __restrict__ Yh)
{
    __shared__ __align__(16) short SM[2][8192];   // 32 KB: 2 bufs x {Kh,Vh}

    const int tid = threadIdx.x, lane = tid & 63, wid = tid >> 6;
    const int l31 = lane & 31, l5 = lane >> 5;
    const int bid = blockIdx.x;
    const int qb = 15 - (bid >> 5), bh = bid & 31;   // heavy q-tiles first
    const int Q0 = qb * 128;
    const int qg = Q0 + wid * 32 + l31;              // this lane's q row

    // Q fragments from global (once per block)
    s16x8 qfh[4];
    {
        const size_t qo = ((size_t)bh * SEQ + qg) * DH;
#pragma unroll
        for (int t = 0; t < 4; ++t) {
            const int ch = t * 2 + l5;
            qfh[t] = *(const s16x8*)&Qh_g[qo + ch * 8];
        }
    }

    float m_i = -INFINITY, l_i = 0.f;
    f32x16 yacc[2];
#pragma unroll
    for (int e = 0; e < 16; ++e) { yacc[0][e] = 0.f; yacc[1][e] = 0.f; }

    const int srow = lane >> 3, ss = lane & 7;
    const int KT = 2 * qb + 2;

    {
#pragma unroll
        for (int i = 0; i < 4; ++i) {
            const int s = wid * 4 + i;
            const int t = s >> 3, j = s & 7;
            const int row = j * 8 + srow;
            const int kc = ss ^ (row & 7);
            const unsigned short* src = (t == 0)
                ? Kh_g + ((size_t)bh * SEQ + row) * DH + kc * 8
                : Vh_g + ((size_t)bh * DH + row) * SEQ + kc * 8;
            gload16(src, &SM[0][t * 4096 + j * 512]);
        }
    }

    for (int kt = 0; kt < KT; ++kt) {
        const int cur = kt & 1;
        __syncthreads();   // stage(kt) landed; reads of buf[cur] (kt-2) done
        if (kt + 1 < KT) {
            const int kn = (kt + 1) * 64;
#pragma unroll
            for (int i = 0; i < 4; ++i) {
                const int s = wid * 4 + i;
                const int t = s >> 3, j = s & 7;
                const int row = j * 8 + srow;
                const int kc = ss ^ (row & 7);
                const unsigned short* src = (t == 0)
                    ? Kh_g + ((size_t)bh * SEQ + kn + row) * DH + kc * 8
                    : Vh_g + ((size_t)bh * DH + row) * SEQ + kn + kc * 8;
                gload16(src, &SM[cur ^ 1][t * 4096 + j * 512]);
            }
        }

        if (kt * 64 > Q0 + wid * 32 + 31) continue;   // fully masked for this wave

        const short* Ksh = &SM[cur][0];
        const short* Vsh = &SM[cur][4096];

        // ---- S^T = K . Q  (1-combo; interleaved kb -> distance-2 chains)
        f32x16 s[2];
#pragma unroll
        for (int e = 0; e < 16; ++e) { s[0][e] = 0.f; s[1][e] = 0.f; }
#pragma unroll
        for (int t = 0; t < 4; ++t) {
            s16x8 kh[2];
#pragma unroll
            for (int kb = 0; kb < 2; ++kb) {
                const int row = kb * 32 + l31;
                const int sl = ((t * 2 + l5) ^ (row & 7)) * 8;
                kh[kb] = *(const s16x8*)&Ksh[row * 64 + sl];
            }
#pragma unroll
            for (int kb = 0; kb < 2; ++kb) s[kb] = MFMA32(kh[kb], qfh[t], s[kb]);
        }

        // ---- causal mask (only near the diagonal)
        if (kt * 64 + 63 > Q0 + wid * 32) {
#pragma unroll
            for (int kb = 0; kb < 2; ++kb)
#pragma unroll
                for (int r = 0; r < 16; ++r) {
                    const int key = kt * 64 + kb * 32 + (r & 3) + 8 * (r >> 2) + 4 * l5;
                    if (key > qg) s[kb][r] = -INFINITY;
                }
        }

        // ---- online softmax in exp2 units, defer-max THR=8 (P <= 2^8)
        float mx = s[0][0];
#pragma unroll
        for (int r = 1; r < 16; ++r) mx = fmaxf(mx, s[0][r]);
#pragma unroll
        for (int r = 0; r < 16; ++r) mx = fmaxf(mx, s[1][r]);
        mx = fmaxf(mx, __shfl_xor(mx, 32));
        const bool defer = (__all(mx - m_i <= 8.f) != 0);
        float mref;
        if (defer) {
            mref = m_i;
        } else {
            mref = fmaxf(m_i, mx);
            const float al = EXP2(m_i - mref);
            m_i = mref;
            l_i *= al;
#pragma unroll
            for (int e = 0; e < 16; ++e) { yacc[0][e] *= al; yacc[1][e] *= al; }
        }
        float ls = 0.f;
#pragma unroll
        for (int kb = 0; kb < 2; ++kb)
#pragma unroll
            for (int r = 0; r < 16; ++r) {
                s[kb][r] = EXP2(s[kb][r] - mref);
                ls += s[kb][r];
            }
        ls += __shfl_xor(ls, 32);
        l_i += ls;

        // ---- P (bf16) fragments in-register: cvt_pk + permlane32_swap
        unsigned pk[2][8];
#pragma unroll
        for (int kb = 0; kb < 2; ++kb)
#pragma unroll
            for (int j = 0; j < 8; ++j)
                pk[kb][j] = cvt_pk_bf16(s[kb][2 * j], s[kb][2 * j + 1]);
        s16x8 pf[2][2];
#pragma unroll
        for (int kb = 0; kb < 2; ++kb) {
            u32x2 sA = __builtin_amdgcn_permlane32_swap(pk[kb][0], pk[kb][2], false, false);
            u32x2 sB = __builtin_amdgcn_permlane32_swap(pk[kb][1], pk[kb][3], false, false);
            u32x4 w0 = {sA[0], sB[0], sA[1], sB[1]};
            pf[kb][0] = __builtin_bit_cast(s16x8, w0);
            u32x2 sC = __builtin_amdgcn_permlane32_swap(pk[kb][4], pk[kb][6], false, false);
            u32x2 sD = __builtin_amdgcn_permlane32_swap(pk[kb][5], pk[kb][7], false, false);
            u32x4 w1 = {sC[0], sD[0], sC[1], sD[1]};
            pf[kb][1] = __builtin_bit_cast(s16x8, w1);
        }

        // ---- Y^T += V^T . P  (1-combo; interleaved dt -> distance-2 chains)
#pragma unroll
        for (int t = 0; t < 4; ++t) {
            s16x8 vh[2];
#pragma unroll
            for (int dt = 0; dt < 2; ++dt) {
                const int row = dt * 32 + l31;
                const int sl = ((t * 2 + l5) ^ (row & 7)) * 8;
                vh[dt] = *(const s16x8*)&Vsh[row * 64 + sl];
            }
            const s16x8 pfr = pf[t >> 1][t & 1];
#pragma unroll
            for (int dt = 0; dt < 2; ++dt) yacc[dt] = MFMA32(vh[dt], pfr, yacc[dt]);
        }
    }

    // ---- epilogue: normalize, hi-only bf16, LDS transpose bounce, write Yh
    __syncthreads();   // everyone done with K/V LDS
    short* SMf = &SM[0][0];
    const float inv = 1.f / l_i;
    const int qlcl = wid * 32 + l31;
#pragma unroll
    for (int dt = 0; dt < 2; ++dt)
#pragma unroll
        for (int rq = 0; rq < 4; ++rq) {
            const int d0 = dt * 32 + rq * 8 + 4 * l5;
            s16x4 h4;
#pragma unroll
            for (int c = 0; c < 4; ++c)
                h4[c] = (short)bf16_rne(yacc[dt][rq * 4 + c] * inv);
            const int base = qlcl * 64 + (((d0 >> 3) ^ (qlcl & 7)) * 8) + (d0 & 7);
            *(s16x4*)&SMf[base] = h4;
        }
    __syncthreads();
    const int b = bh >> 4, h = bh & 15;
#pragma unroll
    for (int i = 0; i < 4; ++i) {
        const int idx = tid + i * 256;
        const int row = idx >> 3, ch = idx & 7;
        const int sl = (ch ^ (row & 7)) * 8;
        s16x8 vh8 = *(const s16x8*)&SMf[row * 64 + sl];
        const size_t o = ((size_t)(b * SEQ + Q0 + row)) * EMBED + h * DH + ch * 8;
        *(s16x8*)&Yh[o] = vh8;
    }
}

// ---------------------------------------------------------------------------
// Out GEMM: pure bf16, 128x64 tile (grid 512 = 2 blocks/CU), dbuf 24 KB,
// 12-segment issue-early staging (3/wave), XCD swizzle (4m x 16n per XCD).
// ---------------------------------------------------------------------------
__global__ __launch_bounds__(256)
void out_gemm_kernel(const unsigned short* __restrict__ Yh_g,
                     const unsigned short* __restrict__ WhT,
                     const float* __restrict__ bias, float* __restrict__ out)
{
    constexpr int KD = 1024, ND = 1024;
    // per buf (shorts): A [0,4096) = [128][32], B [4096,6144) = [64][32]
    __shared__ __align__(16) short SB[2][6144];   // 24 KB

    const int tid = threadIdx.x, lane = tid & 63, wid = tid >> 6;
    const int g = lane >> 4, ln = lane & 15;
    const int wm = wid >> 1, wn = wid & 1;

    const int bid = blockIdx.x;
    const int u = bid >> 3, xcd = bid & 7;
    const int by = xcd * 4 + (u & 3);   // m-tile 0..31
    const int bx = u >> 2;              // n-tile 0..15
    const int m0 = by * 128, n0 = bx * 64;

    f32x4 acc[4][2];
#pragma unroll
    for (int i = 0; i < 4; ++i)
#pragma unroll
        for (int j = 0; j < 2; ++j) acc[i][j] = (f32x4){0.f, 0.f, 0.f, 0.f};

    const int srow = lane >> 2, ss = lane & 3;

    // staging: 12 segments (A x 8, B x 4); 3 per wave
#define OG_STAGE(buf, k0_)                                                     \
    {                                                                          \
        _Pragma("unroll")                                                      \
        for (int i = 0; i < 3; ++i) {                                          \
            const int s = wid * 3 + i;                                         \
            const bool isA = (s < 8);                                          \
            const int j = isA ? s : (s - 8);                                   \
            const int row_loc = j * 16 + srow;                                 \
            const int kc = ss ^ ((row_loc >> 1) & 3);                          \
            const unsigned short* src = isA                                    \
                ? Yh_g + (size_t)(m0 + row_loc) * KD + (k0_) + kc * 8          \
                : WhT + (size_t)(n0 + row_loc) * KD + (k0_) + kc * 8;          \
            gload16(src, &SB[buf][(isA ? 0 : 4096) + j * 512]);                \
        }                                                                      \
    }

    OG_STAGE(0, 0)

    for (int it = 0; it < 32; ++it) {
        const int cur = it & 1;
        __syncthreads();
        if (it + 1 < 32) OG_STAGE(cur ^ 1, (it + 1) * 32)

        const short* Ah = &SB[cur][0];
        const short* Bh = &SB[cur][4096];

        s16x8 fah[4], fbh[2];
#pragma unroll
        for (int am = 0; am < 4; ++am) {
            int m_loc = wm * 64 + am * 16 + ln;
            int sl = (g ^ ((m_loc >> 1) & 3)) * 8;
            fah[am] = *(const s16x8*)&Ah[m_loc * 32 + sl];
        }
#pragma unroll
        for (int bn = 0; bn < 2; ++bn) {
            int n_loc = wn * 32 + bn * 16 + ln;
            int sl = (g ^ ((n_loc >> 1) & 3)) * 8;
            fbh[bn] = *(const s16x8*)&Bh[n_loc * 32 + sl];
        }
#pragma unroll
        for (int am = 0; am < 4; ++am)
#pragma unroll
            for (int bn = 0; bn < 2; ++bn)
                acc[am][bn] = MFMA16(fah[am], fbh[bn], acc[am][bn]);
    }
#undef OG_STAGE

#pragma unroll
    for (int am = 0; am < 4; ++am)
#pragma unroll
        for (int bn = 0; bn < 2; ++bn) {
            int n = n0 + wn * 32 + bn * 16 + ln;
            float bv = bias[n];
#pragma unroll
            for (int r = 0; r < 4; ++r) {
                int m = m0 + wm * 64 + am * 16 + g * 4 + r;
                out[(size_t)m * ND + n] = acc[am][bn][r] + bv;
            }
        }
}

// ---------------------------------------------------------------------------
extern "C" void kernel_launch(void* const* d_in, const int* in_sizes, int n_in,
                              void* d_out, int out_size, void* d_ws, size_t ws_size,
                              hipStream_t stream)
{
    const float* x     = (const float*)d_in[0];
    const float* W_kqv = (const float*)d_in[1];
    const float* b_kqv = (const float*)d_in[2];
    const float* W_out = (const float*)d_in[3];
    const float* b_out = (const float*)d_in[4];
    float* out = (float*)d_out;

    char* ws = (char*)d_ws;
    const size_t MB = 1024 * 1024;
    // ws map (64 MB): Qh [0,8) | WoTh [8,10) | Kh [16,24) | Vh [32,40)
    //                 WhT [48,54) then Yh [48,56) after qkv
    unsigned short* Qh   = (unsigned short*)(ws);
    unsigned short* WoTh = (unsigned short*)(ws + 8 * MB);   // permanently free hole
    unsigned short* Kh   = Qh + 8388608;    // ws+16MB
    unsigned short* Vh   = Kh + 8388608;    // ws+32MB
    unsigned short* WhT  = (unsigned short*)(ws + 48 * MB);
    unsigned short* Yh   = (unsigned short*)(ws + 48 * MB);  // overwrites WhT post-qkv
    // Xh lives in d_out (8 MB of 16): dead until out_gemm rewrites all of it.
    unsigned short* Xh = (unsigned short*)d_out;

    prep_kernel<<<dim3(6144), 256, 0, stream>>>(
        x, W_kqv, W_out, Xh, WhT, WoTh);
    qkv_gemm_kernel<<<dim3(768), 256, 0, stream>>>(
        Xh, WhT, b_kqv, Qh, Kh, Vh);
    attn_kernel<<<dim3(BHTOT * (SEQ / 128)), 256, 0, stream>>>(
        Qh, Kh, Vh, Yh);
    out_gemm_kernel<<<dim3(512), 256, 0, stream>>>(
        Yh, WoTh, b_out, out);
}